// Round 10
// baseline (248.596 us; speedup 1.0000x reference)
//
#include <hip/hip_runtime.h>
#include <hip/hip_bf16.h>
#include <float.h>
#include <math.h>

// B=4, S=4096, D=2048, E=64, K=2
#define B_DIM 4
#define S_DIM 4096
#define D_DIM 2048
#define E_DIM 64
#define N_TOK 16384
#define TOKS 32              // tokens per block
#define NBLK (N_TOK / TOKS)  // 512 blocks (2/CU)
#define NTHR 512             // 8 waves, one per K-slice of 256; barrier-free K-loop
#define WAVES 8              // split-K factor
#define KSTEPS 8             // K=32 per step, single-buffered private tile per wave
#define GAP_THRESH 1e-3f
#define MAXFLAG 16

typedef __bf16 bf16x8_t __attribute__((ext_vector_type(8)));
typedef float f32x4_t __attribute__((ext_vector_type(4)));

union U8 { bf16x8_t v; unsigned short u[8]; };

// truncating fp32 -> (bf16 hi, bf16 lo) split; hi+lo captures ~16 mantissa bits
__device__ __forceinline__ void split2(float f, unsigned short& h, unsigned short& l) {
    unsigned int u = __float_as_uint(f);
    h = (unsigned short)(u >> 16);
    float hf = __uint_as_float(u & 0xFFFF0000u);
    l = (unsigned short)(__float_as_uint(f - hf) >> 16);  // exact residual (Sterbenz)
}

// async 16B global->LDS DMA (no VGPR round-trip, no spill pressure)
typedef const __attribute__((address_space(1))) unsigned int* gas1_t;
typedef __attribute__((address_space(3))) unsigned int* las3_t;
__device__ __forceinline__ void gll16(const unsigned short* g, unsigned short* l) {
    __builtin_amdgcn_global_load_lds((gas1_t)(const void*)g, (las3_t)(void*)l, 16, 0, 0);
}

// one-time W -> (hi,lo) bf16 planes in MFMA-fragment order (verified rounds 3/5-9):
//   chunk c (2048 contiguous elems at c*2048) covers k in [c*32, c*32+32) for all
//   64 experts, fragment-ordered: elem = c*2048 + t*512 + lane*8 + j,
//   expert e = t*16 + (lane&15), k = c*32 + (lane>>4)*8 + j.
// Block 0 also zeros the ws header (zsum, load sums).
__global__ void wsplit(const float* __restrict__ W, unsigned short* __restrict__ wh,
                       unsigned short* __restrict__ wl, float* __restrict__ wshdr) {
    const int i = blockIdx.x * 256 + threadIdx.x;   // 0..16383
    if (blockIdx.x == 0) { wshdr[threadIdx.x] = 0.f; wshdr[threadIdx.x + 256] = 0.f; }
    const int e    = i >> 8;        // expert row 0..63
    const int k8   = i & 255;       // 8-float chunk 0..255
    const int quad = k8 & 3;
    const int h    = (k8 >> 2) & 1;
    const int s    = (k8 >> 3) & 7;
    const int sl   = k8 >> 6;
    const int t    = e >> 4;
    const int l15  = e & 15;
    const int lane = quad * 16 + l15;
    const size_t f = ((size_t)((sl * 8 + s) * 2 + h) * 4 + t) * 64 + lane;
    float4 a = *(const float4*)(W + (size_t)e * D_DIM + k8 * 8);
    float4 b = *(const float4*)(W + (size_t)e * D_DIM + k8 * 8 + 4);
    ushort4 h0, l0, h1, l1;
    split2(a.x, h0.x, l0.x); split2(a.y, h0.y, l0.y);
    split2(a.z, h0.z, l0.z); split2(a.w, h0.w, l0.w);
    split2(b.x, h1.x, l1.x); split2(b.y, h1.y, l1.y);
    split2(b.z, h1.z, l1.z); split2(b.w, h1.w, l1.w);
    *(ushort4*)(wh + f * 8)     = h0;
    *(ushort4*)(wh + f * 8 + 4) = h1;
    *(ushort4*)(wl + f * 8)     = l0;
    *(ushort4*)(wl + f * 8 + 4) = l1;
}

__global__ __launch_bounds__(NTHR, 4) void router_main(
    const float* __restrict__ x, const float* __restrict__ W,
    const unsigned short* __restrict__ whg, const unsigned short* __restrict__ wlg,
    const float* __restrict__ gamma, const float* __restrict__ beta,
    const float* __restrict__ temperature,
    float* __restrict__ out_rw, float* __restrict__ out_dp,
    float* __restrict__ g_zsum, float* __restrict__ g_load)
{
    // 66 KB arena: 8 per-wave private single-buffered W tiles (hi 32K + lo 32K)
    // during the K-loop; 8 split-K partial planes afterwards (aliased).
    __shared__ __align__(16) unsigned char arena[WAVES * TOKS * (E_DIM + 2) * 4]; // 67584
    unsigned short* const bufH = (unsigned short*)arena;            // [wv][2048]
    unsigned short* const bufL = (unsigned short*)(arena + 32768);  // [wv][2048]
    float (* const part)[TOKS][E_DIM + 2] = (float (*)[TOKS][E_DIM + 2])arena; // [8][32][66]

    __shared__ float lgt[TOKS][E_DIM + 1];
    __shared__ float lgm[E_DIM], lbt[E_DIM], loadsum[E_DIM];
    __shared__ float smu[TOKS], srs[TOKS], sinv[TOKS];
    __shared__ int sel1[TOKS], sel2[TOKS];
    __shared__ int ftok[MAXFLAG], fcand[MAXFLAG][3];
    __shared__ int nflag;

    const int tid = threadIdx.x;
    const int tokBase = blockIdx.x * TOKS;
    const int lane = tid & 63;
    const int wv = tid >> 6;       // 0..7 == K-slice (k in [wv*256, wv*256+256))
    const int l15 = lane & 15;
    const int quad = lane >> 4;

    if (tid == 0) nflag = 0;
    if (tid < E_DIM) { lgm[tid] = gamma[tid]; lbt[tid] = beta[tid]; loadsum[tid] = 0.f; }

    // x per-lane A-fragment bases, one per token half: row = token, col = wv*256 + quad*8
    const float* xp0 = x + (size_t)(tokBase + l15) * D_DIM      + wv * 256 + quad * 8;
    const float* xp1 = x + (size_t)(tokBase + 16 + l15) * D_DIM + wv * 256 + quad * 8;

    // this wave's private staging: chunk (wv*8 + s) = 2048 contiguous elems per plane;
    // dst = wave-uniform base + lane*16B (matches global_load_lds HW pattern)
    const unsigned short* hsrc0 = whg + (size_t)wv * 8 * 2048 + lane * 8;
    const unsigned short* lsrc0 = wlg + (size_t)wv * 8 * 2048 + lane * 8;
    unsigned short* const hdst = bufH + wv * 2048 + lane * 8;
    unsigned short* const ldst = bufL + wv * 2048 + lane * 8;
    const unsigned short* const hb = bufH + wv * 2048;   // read base (this wave's tile)
    const unsigned short* const lb = bufL + wv * 2048;

#define STAGE(S) do {                                                       \
        const unsigned short* hs = hsrc0 + (size_t)(S) * 2048;              \
        const unsigned short* ls = lsrc0 + (size_t)(S) * 2048;              \
        gll16(hs,        hdst);        gll16(ls,        ldst);              \
        gll16(hs +  512, hdst +  512); gll16(ls +  512, ldst +  512);       \
        gll16(hs + 1024, hdst + 1024); gll16(ls + 1024, ldst + 1024);       \
        gll16(hs + 1536, hdst + 1536); gll16(ls + 1536, ldst + 1536);       \
    } while (0)

    f32x4_t acc[2][4];
    #pragma unroll
    for (int m = 0; m < 2; ++m)
        #pragma unroll
        for (int t = 0; t < 4; ++t) acc[m][t] = (f32x4_t){0.f, 0.f, 0.f, 0.f};

    // ---- barrier-free per-wave K-loop, 8 steps of K=32 ----
    // Single-buffered tile: per step, ds_read tile(s) -> lgkmcnt(0) -> refill with
    // tile(s+1) (DMA latency hides under the 24-MFMA block) -> vmcnt(4) keeps
    // x(s+2) (4 loads) in flight across the step boundary (never drain to 0).
    float4 xqA[4], xqB[4], xqC[4];
    STAGE(0);                                              // 8 DMA (oldest)
    xqA[0] = *(const float4*)(xp0);      xqA[1] = *(const float4*)(xp0 + 4);
    xqA[2] = *(const float4*)(xp1);      xqA[3] = *(const float4*)(xp1 + 4);
    xqB[0] = *(const float4*)(xp0 + 32); xqB[1] = *(const float4*)(xp0 + 36);
    xqB[2] = *(const float4*)(xp1 + 32); xqB[3] = *(const float4*)(xp1 + 36);
    asm volatile("s_waitcnt vmcnt(4)" ::: "memory");       // W(0)+x(0) done; x(1) flies
    __builtin_amdgcn_sched_barrier(0);

    #pragma unroll
    for (int s = 0; s < KSTEPS; ++s) {
        // ds_read this step's fragments (conflict-free lane-contiguous b128)
        bf16x8_t bh[4], bl[4];
        #pragma unroll
        for (int t = 0; t < 4; ++t) {
            bh[t] = *(const bf16x8_t*)(hb + t * 512 + lane * 8);
            bl[t] = *(const bf16x8_t*)(lb + t * 512 + lane * 8);
        }
        __builtin_amdgcn_sched_barrier(0);
        asm volatile("s_waitcnt lgkmcnt(0)" ::: "memory"); // reads retired -> safe refill
        __builtin_amdgcn_sched_barrier(0);
        if (s + 1 < KSTEPS) STAGE(s + 1);                  // refill same buffer
        if (s + 2 < KSTEPS) {                              // x two steps ahead
            const float* xg0 = xp0 + (s + 2) * 32;
            const float* xg1 = xp1 + (s + 2) * 32;
            xqC[0] = *(const float4*)(xg0);  xqC[1] = *(const float4*)(xg0 + 4);
            xqC[2] = *(const float4*)(xg1);  xqC[3] = *(const float4*)(xg1 + 4);
        }
        // compute (covers the refill DMA's L2 latency)
        #pragma unroll
        for (int m = 0; m < 2; ++m) {
            float tf[8] = {xqA[m*2].x, xqA[m*2].y, xqA[m*2].z, xqA[m*2].w,
                           xqA[m*2+1].x, xqA[m*2+1].y, xqA[m*2+1].z, xqA[m*2+1].w};
            U8 ah, al;
            #pragma unroll
            for (int k = 0; k < 8; ++k) split2(tf[k], ah.u[k], al.u[k]);
            #pragma unroll
            for (int t = 0; t < 4; ++t) {
                acc[m][t] = __builtin_amdgcn_mfma_f32_16x16x32_bf16(ah.v, bh[t], acc[m][t], 0, 0, 0);
                acc[m][t] = __builtin_amdgcn_mfma_f32_16x16x32_bf16(ah.v, bl[t], acc[m][t], 0, 0, 0);
                acc[m][t] = __builtin_amdgcn_mfma_f32_16x16x32_bf16(al.v, bh[t], acc[m][t], 0, 0, 0);
            }
        }
        if (s + 2 < KSTEPS) {
            asm volatile("s_waitcnt vmcnt(4)" ::: "memory");   // W(s+1)+x(s+1) done
        } else if (s + 1 < KSTEPS) {
            asm volatile("s_waitcnt vmcnt(0)" ::: "memory");   // tail drain
        }
        __builtin_amdgcn_sched_barrier(0);
        if (s + 1 < KSTEPS) {
            #pragma unroll
            for (int j = 0; j < 4; ++j) { xqA[j] = xqB[j]; xqB[j] = xqC[j]; }
        }
    }
#undef STAGE

    __syncthreads();   // all waves done with their buffers; safe to alias as 'part'

    // phase A: partial acc -> LDS.  C/D: col(n)=lane&15, row(m)=quad*4+reg
    #pragma unroll
    for (int m = 0; m < 2; ++m)
        #pragma unroll
        for (int t = 0; t < 4; ++t)
            #pragma unroll
            for (int r = 0; r < 4; ++r)
                part[wv][m * 16 + quad * 4 + r][t * 16 + l15] = acc[m][t][r];
    __syncthreads();

    // split-K reduction: 8 partials -> logits (fixed pairwise order, deterministic)
    for (int i = tid; i < TOKS * E_DIM; i += NTHR) {
        int r = i >> 6, c = i & 63;
        lgt[r][c] = ((part[0][r][c] + part[1][r][c]) + (part[2][r][c] + part[3][r][c]))
                  + ((part[4][r][c] + part[5][r][c]) + (part[6][r][c] + part[7][r][c]));
    }
    __syncthreads();

    // phase B: waves 0-1 only; 4 lanes per token (quad = expert quarter)
    if (wv < 2) {
        const int tok = wv * 16 + l15;
        const int q = quad;
        const float it = 1.f / (temperature[0] + 1e-6f);
        float s1 = 0.f, s2 = 0.f;
        #pragma unroll
        for (int e = 0; e < 16; ++e) { float v = lgt[tok][q * 16 + e]; s1 += v; s2 += v * v; }
        s1 += __shfl_xor(s1, 16); s1 += __shfl_xor(s1, 32);
        s2 += __shfl_xor(s2, 16); s2 += __shfl_xor(s2, 32);
        const float mu  = s1 * (1.f / 64.f);
        const float var = s2 * (1.f / 64.f) - mu * mu;   // biased, matches ref
        const float rs  = rsqrtf(var + 1e-5f);
        if (q == 0) { smu[tok] = mu; srs[tok] = rs; }

        float m0 = -FLT_MAX, m1 = -FLT_MAX, m2 = -FLT_MAX;
        int   i0 = -1, i1 = -1, i2 = -1;
        float zl = 0.f;
        #pragma unroll
        for (int e = 0; e < 16; ++e) {
            int c = q * 16 + e;
            float y = (lgt[tok][c] - mu) * rs * lgm[c] + lbt[c];
            lgt[tok][c] = y;
            zl += y * y;
            if (y > m0)      { m2 = m1; i2 = i1; m1 = m0; i1 = i0; m0 = y; i0 = c; }
            else if (y > m1) { m2 = m1; i2 = i1; m1 = y; i1 = c; }
            else if (y > m2) { m2 = y; i2 = c; }
        }
        // merge sorted top-3 triples across quad lanes (3+3 merge, low-index tie-break)
        #pragma unroll
        for (int d = 16; d <= 32; d <<= 1) {
            float n0 = __shfl_xor(m0, d), n1 = __shfl_xor(m1, d), n2 = __shfl_xor(m2, d);
            int   j0 = __shfl_xor(i0, d), j1 = __shfl_xor(i1, d), j2 = __shfl_xor(i2, d);
            bool t0 = (m0 > n0) || (m0 == n0 && i0 < j0);
            float r0v = t0 ? m0 : n0; int r0i = t0 ? i0 : j0;
            float A0v = t0 ? m1 : m0; int A0i = t0 ? i1 : i0;
            float A1v = t0 ? m2 : m1; int A1i = t0 ? i2 : i1;
            float B0v = t0 ? n0 : n1; int B0i = t0 ? j0 : j1;
            float B1v = t0 ? n1 : n2; int B1i = t0 ? j1 : j2;
            bool t1 = (A0v > B0v) || (A0v == B0v && A0i < B0i);
            float r1v = t1 ? A0v : B0v; int r1i = t1 ? A0i : B0i;
            float A0w = t1 ? A1v : A0v; int A0j = t1 ? A1i : A0i;
            float B0w = t1 ? B0v : B1v; int B0j = t1 ? B0i : B1i;
            bool t2 = (A0w > B0w) || (A0w == B0w && A0j < B0j);
            float r2v = t2 ? A0w : B0w; int r2i = t2 ? A0j : B0j;
            m0 = r0v; i0 = r0i; m1 = r1v; i1 = r1i; m2 = r2v; i2 = r2i;
        }
        if (q == 0) {
            sel1[tok] = i0; sel2[tok] = i1;
            if (m1 - m2 < GAP_THRESH) {   // rank2/rank3 near-tie -> fp64 fix-up
                int sf = atomicAdd(&nflag, 1);
                if (sf < MAXFLAG) { ftok[sf] = tok; fcand[sf][0] = i0; fcand[sf][1] = i1; fcand[sf][2] = i2; }
            }
        }
        // softmax (store unnormalized exp; scale at write time)
        float es = 0.f;
        #pragma unroll
        for (int e = 0; e < 16; ++e) {
            int c = q * 16 + e;
            float ev = __expf((lgt[tok][c] - m0) * it);
            lgt[tok][c] = ev; es += ev;
        }
        es += __shfl_xor(es, 16); es += __shfl_xor(es, 32);
        if (q == 0) sinv[tok] = 1.f / es;
        // z-loss: full-wave reduce (covers this wave's 16 tokens x 64 experts)
        zl += __shfl_xor(zl, 1); zl += __shfl_xor(zl, 2); zl += __shfl_xor(zl, 4);
        zl += __shfl_xor(zl, 8); zl += __shfl_xor(zl, 16); zl += __shfl_xor(zl, 32);
        if (lane == 0) atomicAdd(g_zsum, zl);
    }
    __syncthreads();

    // phase C: cooperative fp64 re-rank of flagged tokens' top-3 candidates (8 waves)
    const int nf = min(nflag, MAXFLAG);
    for (int f = wv; f < nf; f += 8) {
        const int tk = ftok[f];
        const int c0 = fcand[f][0], c1 = fcand[f][1], c2 = fcand[f][2];
        const float* xr = x + (size_t)(tokBase + tk) * D_DIM;
        const float* w0 = W + (size_t)c0 * D_DIM;
        const float* w1 = W + (size_t)c1 * D_DIM;
        const float* w2 = W + (size_t)c2 * D_DIM;
        double L0 = 0.0, L1 = 0.0, L2 = 0.0;
        for (int i = lane; i < D_DIM; i += 64) {
            double xv = (double)xr[i];
            L0 += xv * (double)w0[i];
            L1 += xv * (double)w1[i];
            L2 += xv * (double)w2[i];
        }
        #pragma unroll
        for (int off = 32; off; off >>= 1) {
            L0 += __shfl_down(L0, off);
            L1 += __shfl_down(L1, off);
            L2 += __shfl_down(L2, off);
        }
        if (lane == 0) {
            double dmu = (double)smu[tk], drs = (double)srs[tk];
            double y0 = (L0 - dmu) * drs * (double)lgm[c0] + (double)lbt[c0];
            double y1 = (L1 - dmu) * drs * (double)lgm[c1] + (double)lbt[c1];
            double y2 = (L2 - dmu) * drs * (double)lgm[c2] + (double)lbt[c2];
            bool g01 = (y0 > y1) || (y0 == y1 && c0 < c1);
            bool g02 = (y0 > y2) || (y0 == y2 && c0 < c2);
            bool g12 = (y1 > y2) || (y1 == y2 && c1 < c2);
            int a, b;
            if (!g01 && !g02)      { a = c1; b = c2; }   // elem0 loses both
            else if (g01 && !g12)  { a = c0; b = c2; }   // elem1 loses both
            else                   { a = c0; b = c1; }   // elem2 loses both
            sel1[tk] = a; sel2[tk] = b;
        }
    }
    __syncthreads();

    // phase D: expert-load accumulation (selection-dependent, post-fix-up)
    if (tid < TOKS) {
        float inv = sinv[tid];
        atomicAdd(&loadsum[sel1[tid]], lgt[tid][sel1[tid]] * inv);
        atomicAdd(&loadsum[sel2[tid]], lgt[tid][sel2[tid]] * inv);
    }
    __syncthreads();
    if (tid < E_DIM) atomicAdd(&g_load[(tokBase >> 12) * E_DIM + tid], loadsum[tid]);

    // phase E: coalesced outputs (8 KB per array per block)
    float* orw = out_rw + (size_t)tokBase * E_DIM;
    float* odp = out_dp + (size_t)tokBase * E_DIM;
    for (int i = tid; i < TOKS * E_DIM; i += NTHR) {
        int r = i >> 6, c = i & 63;
        float p = lgt[r][c] * sinv[r];
        orw[i] = p;
        odp[i] = (c == sel1[r] || c == sel2[r]) ? p : 0.f;
    }
}

__global__ void router_fin(const float* __restrict__ ws, float* __restrict__ out_loss) {
    __shared__ float sv[B_DIM * E_DIM];
    const int tid = threadIdx.x;
    sv[tid] = ws[8 + tid] * (1.f / S_DIM);   // expert_load[b][e]
    __syncthreads();
    if (tid == 0) {
        float s = 0.f;
        for (int i = 0; i < B_DIM * E_DIM; ++i) s += sv[i];
        const float mean = s * (1.f / (B_DIM * E_DIM));
        float ss = 0.f;
        for (int i = 0; i < B_DIM * E_DIM; ++i) { float d = sv[i] - mean; ss += d * d; }
        const float sd = sqrtf(ss * (1.f / (B_DIM * E_DIM - 1)));  // ddof=1
        const float z = ws[0] * (1.f / ((float)N_TOK * E_DIM));
        out_loss[0] = 0.001f * z + 0.1f * (sd / mean) * 10.f;
    }
}

extern "C" void kernel_launch(void* const* d_in, const int* in_sizes, int n_in,
                              void* d_out, int out_size, void* d_ws, size_t ws_size,
                              hipStream_t stream) {
    const float* x     = (const float*)d_in[0];
    const float* W     = (const float*)d_in[1];
    const float* gamma = (const float*)d_in[2];
    const float* beta  = (const float*)d_in[3];
    const float* temp  = (const float*)d_in[4];
    float* out  = (float*)d_out;
    float* rw   = out;                                  // routing_weights [N, E]
    float* dp   = out + (size_t)N_TOK * E_DIM;          // dispatch [B, S, E]
    float* loss = out + 2 * (size_t)N_TOK * E_DIM;      // total_loss scalar
    float* ws   = (float*)d_ws;   // [0]=zsum, [8..264)=load sums

    // workspace layout: [0,2KB) header | [4KB, +256KB) W-hi frag-order | +256KB W-lo
    unsigned short* whg = (unsigned short*)((char*)d_ws + 4096);
    unsigned short* wlg = whg + (size_t)E_DIM * D_DIM;

    wsplit<<<dim3(64), dim3(256), 0, stream>>>(W, whg, wlg, ws);  // also zeros header
    router_main<<<dim3(NBLK), dim3(NTHR), 0, stream>>>(x, W, whg, wlg, gamma, beta, temp,
                                                       rw, dp, ws, ws + 8);
    router_fin<<<dim3(1), dim3(256), 0, stream>>>(ws, loss);
}

// Round 11
// 243.896 us; speedup vs baseline: 1.0193x; 1.0193x over previous
//
#include <hip/hip_runtime.h>
#include <hip/hip_bf16.h>
#include <float.h>
#include <math.h>

// B=4, S=4096, D=2048, E=64, K=2
#define B_DIM 4
#define S_DIM 4096
#define D_DIM 2048
#define E_DIM 64
#define N_TOK 16384
#define TOKS 32              // tokens per block
#define NBLK (N_TOK / TOKS)  // 512 blocks (2/CU)
#define NTHR 512             // 8 waves: (token-half g) x (D-slice sl)
#define SLICES 4             // split-K factor
#define DSLICE (D_DIM / SLICES)  // 512
#define KSTEPS2 16           // K=32 per step, double-buffered LDS
#define NCOPY 32             // W-plane replication (breaks L2 same-line contention)
#define WPLANE (E_DIM * D_DIM)   // 131072 elems per plane copy
#define GAP_THRESH 1e-3f
#define MAXFLAG 16

typedef __bf16 bf16x8_t __attribute__((ext_vector_type(8)));
typedef float f32x4_t __attribute__((ext_vector_type(4)));

union U8 { bf16x8_t v; unsigned short u[8]; };

// truncating fp32 -> (bf16 hi, bf16 lo) split; hi+lo captures ~16 mantissa bits
__device__ __forceinline__ void split2(float f, unsigned short& h, unsigned short& l) {
    unsigned int u = __float_as_uint(f);
    h = (unsigned short)(u >> 16);
    float hf = __uint_as_float(u & 0xFFFF0000u);
    l = (unsigned short)(__float_as_uint(f - hf) >> 16);  // exact residual (Sterbenz)
}

// async 16B global->LDS DMA (no VGPR round-trip, no spill pressure)
typedef const __attribute__((address_space(1))) unsigned int* gas1_t;
typedef __attribute__((address_space(3))) unsigned int* las3_t;
__device__ __forceinline__ void gll16(const unsigned short* g, unsigned short* l) {
    __builtin_amdgcn_global_load_lds((gas1_t)(const void*)g, (las3_t)(void*)l, 16, 0, 0);
}

// one-time W -> (hi,lo) bf16 planes in MFMA-fragment order (verified rounds 3/5-10),
// replicated NCOPY times so concurrent blocks don't serialize on the same L2 lines.
//   elem offset = (((sl*8 + s)*2 + h)*4 + t)*512 + lane*8,  lane = quad*16 + l15
//   element source: expert e = t*16+l15, k = sl*512 + s*64 + h*32 + quad*8 + j
// Block 0 also zeros the ws header (zsum, load sums).
__global__ void wsplit(const float* __restrict__ W, unsigned short* __restrict__ wh,
                       unsigned short* __restrict__ wl, float* __restrict__ wshdr) {
    const int i = blockIdx.x * 256 + threadIdx.x;   // 0..16383
    if (blockIdx.x == 0) { wshdr[threadIdx.x] = 0.f; wshdr[threadIdx.x + 256] = 0.f; }
    const int e    = i >> 8;        // expert row 0..63
    const int k8   = i & 255;       // 8-float chunk 0..255
    const int quad = k8 & 3;
    const int h    = (k8 >> 2) & 1;
    const int s    = (k8 >> 3) & 7;
    const int sl   = k8 >> 6;
    const int t    = e >> 4;
    const int l15  = e & 15;
    const int lane = quad * 16 + l15;
    const size_t f = ((size_t)((sl * 8 + s) * 2 + h) * 4 + t) * 64 + lane;
    float4 a = *(const float4*)(W + (size_t)e * D_DIM + k8 * 8);
    float4 b = *(const float4*)(W + (size_t)e * D_DIM + k8 * 8 + 4);
    ushort4 h0, l0, h1, l1;
    split2(a.x, h0.x, l0.x); split2(a.y, h0.y, l0.y);
    split2(a.z, h0.z, l0.z); split2(a.w, h0.w, l0.w);
    split2(b.x, h1.x, l1.x); split2(b.y, h1.y, l1.y);
    split2(b.z, h1.z, l1.z); split2(b.w, h1.w, l1.w);
    #pragma unroll 4
    for (int c = 0; c < NCOPY; ++c) {
        unsigned short* whc = wh + (size_t)c * WPLANE;
        unsigned short* wlc = wl + (size_t)c * WPLANE;
        *(ushort4*)(whc + f * 8)     = h0;
        *(ushort4*)(whc + f * 8 + 4) = h1;
        *(ushort4*)(wlc + f * 8)     = l0;
        *(ushort4*)(wlc + f * 8 + 4) = l1;
    }
}

__global__ __launch_bounds__(NTHR, 4) void router_main(
    const float* __restrict__ x, const float* __restrict__ W,
    const unsigned short* __restrict__ whg0, const unsigned short* __restrict__ wlg0,
    const float* __restrict__ gamma, const float* __restrict__ beta,
    const float* __restrict__ temperature,
    float* __restrict__ out_rw, float* __restrict__ out_dp,
    float* __restrict__ g_zsum, float* __restrict__ g_load)
{
    // 64 KB arena: double-buffered W step-tiles (hi+lo, frag-order) during the K-loop;
    // split-K partials + logits afterwards (aliased — barrier separates lifetimes).
    __shared__ __align__(16) unsigned char arena[65536];
    unsigned short* const bufH = (unsigned short*)arena;            // [2][4][2048]
    unsigned short* const bufL = (unsigned short*)(arena + 32768);  // [2][4][2048]
    float (* const part)[TOKS][E_DIM + 2] = (float (*)[TOKS][E_DIM + 2])arena; // [4][32][66]
    float (* const lgt)[E_DIM + 1] = (float (*)[E_DIM + 1])(arena + 33792);    // [32][65]

    __shared__ float lgm[E_DIM], lbt[E_DIM], loadsum[E_DIM];
    __shared__ float smu[TOKS], srs[TOKS], sinv[TOKS];
    __shared__ int sel1[TOKS], sel2[TOKS];
    __shared__ int ftok[MAXFLAG], fcand[MAXFLAG][3];
    __shared__ int nflag;

    const int tid = threadIdx.x;
    const int tokBase = blockIdx.x * TOKS;
    const int lane = tid & 63;
    const int wv = tid >> 6;       // 0..7
    const int g  = wv & 1;         // token half: tokens g*16 .. g*16+15
    const int sl = wv >> 1;        // D-slice 0..3
    const int l15 = lane & 15;
    const int quad = lane >> 4;

    // per-block W copy: consecutive blocks round-robin XCDs, so copy (b&31) gives
    // each XCD 4 private copies (2 MB of its L2) and 16 blocks per copy (was 64+).
    const unsigned short* whg = whg0 + (size_t)(blockIdx.x & (NCOPY - 1)) * WPLANE;
    const unsigned short* wlg = wlg0 + (size_t)(blockIdx.x & (NCOPY - 1)) * WPLANE;

    if (tid == 0) nflag = 0;
    if (tid < E_DIM) { lgm[tid] = gamma[tid]; lbt[tid] = beta[tid]; loadsum[tid] = 0.f; }

    // x per-lane A-fragment base: row = token, col = slice base + quad*8
    const float* xp = x + (size_t)(tokBase + g * 16 + l15) * D_DIM + sl * DSLICE + quad * 8;

    // DMA staging geometry: per step, per plane, tile = 4 slices x 2048 elems (4 KB each).
    // Thread tid covers slices kk0 and kk0+2 at elem offset soff (16 B per lane, linear):
    // LDS dst = wave-uniform base + lane*16B (matches global_load_lds HW pattern).
    const int kk0  = tid >> 8;            // 0..1
    const int soff = (tid & 255) * 8;

    f32x4_t acc[4];
    #pragma unroll
    for (int t = 0; t < 4; ++t) acc[t] = (f32x4_t){0.f, 0.f, 0.f, 0.f};

#define STAGE(S2, B) do {                                                          \
        const size_t gof = (size_t)(S2) * 2048 + soff;                             \
        unsigned short* hB = bufH + (B) * 8192;                                    \
        unsigned short* lB = bufL + (B) * 8192;                                    \
        gll16(whg + (size_t)kk0 * 32768 + gof,       hB + kk0 * 2048 + soff);      \
        gll16(wlg + (size_t)kk0 * 32768 + gof,       lB + kk0 * 2048 + soff);      \
        gll16(whg + (size_t)(kk0 + 2) * 32768 + gof, hB + (kk0 + 2) * 2048 + soff);\
        gll16(wlg + (size_t)(kk0 + 2) * 32768 + gof, lB + (kk0 + 2) * 2048 + soff);\
    } while (0)

    // ---- T3+T4 pipelined K-loop: raw barriers + COUNTED vmcnt (never 0) ----
    // Per-wave VMEM issue order (steady state, iter s): [x(s+1) x2] ... [D(s+2) x4].
    // At the post-STAGE wait, ops newer than D(s+1) = x(s+1)(2) + D(s+2)(4) = 6,
    // so vmcnt(6) forces exactly D(s+1) complete while 6 ops stay in flight.
    // prologue: stage tiles 0 and 1, load x(0); wait D(0) (newer: x(0)x2 + D(1)x4 = 6)
    STAGE(0, 0);
    float4 xqA0 = *(const float4*)(xp);
    float4 xqA1 = *(const float4*)(xp + 4);
    STAGE(1, 1);
    asm volatile("s_waitcnt vmcnt(6)" ::: "memory");
    __builtin_amdgcn_sched_barrier(0);
    __builtin_amdgcn_s_barrier();

    float4 xqB0, xqB1;
    #pragma unroll
    for (int s2 = 0; s2 < KSTEPS2; ++s2) {
        const int cur = s2 & 1;
        if (s2 + 1 < KSTEPS2) {   // issue next x load; consumed next iter
            const float* xg = xp + (s2 + 1) * 32;
            xqB0 = *(const float4*)(xg);
            xqB1 = *(const float4*)(xg + 4);
        }
        // compute tile s2 from buf[cur]: lane-contiguous ds_read_b128, conflict-free
        const unsigned short* hb = bufH + cur * 8192 + sl * 2048;
        const unsigned short* lb = bufL + cur * 8192 + sl * 2048;
        bf16x8_t bh[4], bl[4];
        #pragma unroll
        for (int t = 0; t < 4; ++t) {
            bh[t] = *(const bf16x8_t*)(hb + t * 512 + lane * 8);
            bl[t] = *(const bf16x8_t*)(lb + t * 512 + lane * 8);
        }
        float tf[8] = {xqA0.x, xqA0.y, xqA0.z, xqA0.w, xqA1.x, xqA1.y, xqA1.z, xqA1.w};
        U8 ah, al;
        #pragma unroll
        for (int k = 0; k < 8; ++k) split2(tf[k], ah.u[k], al.u[k]);
        #pragma unroll
        for (int t = 0; t < 4; ++t) {
            acc[t] = __builtin_amdgcn_mfma_f32_16x16x32_bf16(ah.v, bh[t], acc[t], 0, 0, 0);
            acc[t] = __builtin_amdgcn_mfma_f32_16x16x32_bf16(ah.v, bl[t], acc[t], 0, 0, 0);
            acc[t] = __builtin_amdgcn_mfma_f32_16x16x32_bf16(al.v, bh[t], acc[t], 0, 0, 0);
        }
        __builtin_amdgcn_s_barrier();          // all waves done reading buf[cur]
        if (s2 + 2 < KSTEPS2) {
            STAGE(s2 + 2, cur);                // refill the just-freed buffer
            asm volatile("s_waitcnt vmcnt(6)" ::: "memory");   // D(s2+1) done
        } else if (s2 + 1 < KSTEPS2) {
            asm volatile("s_waitcnt vmcnt(2)" ::: "memory");   // tail: only x(s2+1) newer
        }
        __builtin_amdgcn_sched_barrier(0);
        __builtin_amdgcn_s_barrier();          // D(s2+1) visible to all waves
        xqA0 = xqB0; xqA1 = xqB1;
    }
#undef STAGE

    __syncthreads();   // loop done (all DMA landed); protect wbuf -> part alias

    // phase A: partial acc -> LDS.  C/D: col(n)=lane&15, row(m)=quad*4+reg
    #pragma unroll
    for (int t = 0; t < 4; ++t)
        #pragma unroll
        for (int r = 0; r < 4; ++r)
            part[sl][g * 16 + quad * 4 + r][t * 16 + l15] = acc[t][r];
    __syncthreads();

    // split-K reduction: 4 partials -> logits (fixed pairwise order, deterministic)
    for (int i = tid; i < TOKS * E_DIM; i += NTHR) {
        int r = i >> 6, c = i & 63;
        lgt[r][c] = (part[0][r][c] + part[1][r][c]) + (part[2][r][c] + part[3][r][c]);
    }
    __syncthreads();

    // phase B: waves 0-1 only; 4 lanes per token (quad = expert quarter)
    if (wv < 2) {
        const int tok = wv * 16 + l15;
        const int q = quad;
        const float it = 1.f / (temperature[0] + 1e-6f);
        float s1 = 0.f, s2 = 0.f;
        #pragma unroll
        for (int e = 0; e < 16; ++e) { float v = lgt[tok][q * 16 + e]; s1 += v; s2 += v * v; }
        s1 += __shfl_xor(s1, 16); s1 += __shfl_xor(s1, 32);
        s2 += __shfl_xor(s2, 16); s2 += __shfl_xor(s2, 32);
        const float mu  = s1 * (1.f / 64.f);
        const float var = s2 * (1.f / 64.f) - mu * mu;   // biased, matches ref
        const float rs  = rsqrtf(var + 1e-5f);
        if (q == 0) { smu[tok] = mu; srs[tok] = rs; }

        float m0 = -FLT_MAX, m1 = -FLT_MAX, m2 = -FLT_MAX;
        int   i0 = -1, i1 = -1, i2 = -1;
        float zl = 0.f;
        #pragma unroll
        for (int e = 0; e < 16; ++e) {
            int c = q * 16 + e;
            float y = (lgt[tok][c] - mu) * rs * lgm[c] + lbt[c];
            lgt[tok][c] = y;
            zl += y * y;
            if (y > m0)      { m2 = m1; i2 = i1; m1 = m0; i1 = i0; m0 = y; i0 = c; }
            else if (y > m1) { m2 = m1; i2 = i1; m1 = y; i1 = c; }
            else if (y > m2) { m2 = y; i2 = c; }
        }
        // merge sorted top-3 triples across quad lanes (3+3 merge, low-index tie-break)
        #pragma unroll
        for (int d = 16; d <= 32; d <<= 1) {
            float n0 = __shfl_xor(m0, d), n1 = __shfl_xor(m1, d), n2 = __shfl_xor(m2, d);
            int   j0 = __shfl_xor(i0, d), j1 = __shfl_xor(i1, d), j2 = __shfl_xor(i2, d);
            bool t0 = (m0 > n0) || (m0 == n0 && i0 < j0);
            float r0v = t0 ? m0 : n0; int r0i = t0 ? i0 : j0;
            float A0v = t0 ? m1 : m0; int A0i = t0 ? i1 : i0;
            float A1v = t0 ? m2 : m1; int A1i = t0 ? i2 : i1;
            float B0v = t0 ? n0 : n1; int B0i = t0 ? j0 : j1;
            float B1v = t0 ? n1 : n2; int B1i = t0 ? j1 : j2;
            bool t1 = (A0v > B0v) || (A0v == B0v && A0i < B0i);
            float r1v = t1 ? A0v : B0v; int r1i = t1 ? A0i : B0i;
            float A0w = t1 ? A1v : A0v; int A0j = t1 ? A1i : A0i;
            float B0w = t1 ? B0v : B1v; int B0j = t1 ? B0i : B1i;
            bool t2 = (A0w > B0w) || (A0w == B0w && A0j < B0j);
            float r2v = t2 ? A0w : B0w; int r2i = t2 ? A0j : B0j;
            m0 = r0v; i0 = r0i; m1 = r1v; i1 = r1i; m2 = r2v; i2 = r2i;
        }
        if (q == 0) {
            sel1[tok] = i0; sel2[tok] = i1;
            if (m1 - m2 < GAP_THRESH) {   // rank2/rank3 near-tie -> fp64 fix-up
                int sf = atomicAdd(&nflag, 1);
                if (sf < MAXFLAG) { ftok[sf] = tok; fcand[sf][0] = i0; fcand[sf][1] = i1; fcand[sf][2] = i2; }
            }
        }
        // softmax (store unnormalized exp; scale at write time)
        float es = 0.f;
        #pragma unroll
        for (int e = 0; e < 16; ++e) {
            int c = q * 16 + e;
            float ev = __expf((lgt[tok][c] - m0) * it);
            lgt[tok][c] = ev; es += ev;
        }
        es += __shfl_xor(es, 16); es += __shfl_xor(es, 32);
        if (q == 0) sinv[tok] = 1.f / es;
        // z-loss: full-wave reduce (covers this wave's 16 tokens x 64 experts)
        zl += __shfl_xor(zl, 1); zl += __shfl_xor(zl, 2); zl += __shfl_xor(zl, 4);
        zl += __shfl_xor(zl, 8); zl += __shfl_xor(zl, 16); zl += __shfl_xor(zl, 32);
        if (lane == 0) atomicAdd(g_zsum, zl);
    }
    __syncthreads();

    // phase C: cooperative fp64 re-rank of flagged tokens' top-3 candidates (8 waves)
    const int nf = min(nflag, MAXFLAG);
    for (int f = wv; f < nf; f += 8) {
        const int tk = ftok[f];
        const int c0 = fcand[f][0], c1 = fcand[f][1], c2 = fcand[f][2];
        const float* xr = x + (size_t)(tokBase + tk) * D_DIM;
        const float* w0 = W + (size_t)c0 * D_DIM;
        const float* w1 = W + (size_t)c1 * D_DIM;
        const float* w2 = W + (size_t)c2 * D_DIM;
        double L0 = 0.0, L1 = 0.0, L2 = 0.0;
        for (int i = lane; i < D_DIM; i += 64) {
            double xv = (double)xr[i];
            L0 += xv * (double)w0[i];
            L1 += xv * (double)w1[i];
            L2 += xv * (double)w2[i];
        }
        #pragma unroll
        for (int off = 32; off; off >>= 1) {
            L0 += __shfl_down(L0, off);
            L1 += __shfl_down(L1, off);
            L2 += __shfl_down(L2, off);
        }
        if (lane == 0) {
            double dmu = (double)smu[tk], drs = (double)srs[tk];
            double y0 = (L0 - dmu) * drs * (double)lgm[c0] + (double)lbt[c0];
            double y1 = (L1 - dmu) * drs * (double)lgm[c1] + (double)lbt[c1];
            double y2 = (L2 - dmu) * drs * (double)lgm[c2] + (double)lbt[c2];
            bool g01 = (y0 > y1) || (y0 == y1 && c0 < c1);
            bool g02 = (y0 > y2) || (y0 == y2 && c0 < c2);
            bool g12 = (y1 > y2) || (y1 == y2 && c1 < c2);
            int a, b;
            if (!g01 && !g02)      { a = c1; b = c2; }   // elem0 loses both
            else if (g01 && !g12)  { a = c0; b = c2; }   // elem1 loses both
            else                   { a = c0; b = c1; }   // elem2 loses both
            sel1[tk] = a; sel2[tk] = b;
        }
    }
    __syncthreads();

    // phase D: expert-load accumulation (selection-dependent, post-fix-up)
    if (tid < TOKS) {
        float inv = sinv[tid];
        atomicAdd(&loadsum[sel1[tid]], lgt[tid][sel1[tid]] * inv);
        atomicAdd(&loadsum[sel2[tid]], lgt[tid][sel2[tid]] * inv);
    }
    __syncthreads();
    if (tid < E_DIM) atomicAdd(&g_load[(tokBase >> 12) * E_DIM + tid], loadsum[tid]);

    // phase E: coalesced outputs (8 KB per array per block)
    float* orw = out_rw + (size_t)tokBase * E_DIM;
    float* odp = out_dp + (size_t)tokBase * E_DIM;
    for (int i = tid; i < TOKS * E_DIM; i += NTHR) {
        int r = i >> 6, c = i & 63;
        float p = lgt[r][c] * sinv[r];
        orw[i] = p;
        odp[i] = (c == sel1[r] || c == sel2[r]) ? p : 0.f;
    }
}

__global__ void router_fin(const float* __restrict__ ws, float* __restrict__ out_loss) {
    __shared__ float sv[B_DIM * E_DIM];
    const int tid = threadIdx.x;
    sv[tid] = ws[8 + tid] * (1.f / S_DIM);   // expert_load[b][e]
    __syncthreads();
    if (tid == 0) {
        float s = 0.f;
        for (int i = 0; i < B_DIM * E_DIM; ++i) s += sv[i];
        const float mean = s * (1.f / (B_DIM * E_DIM));
        float ss = 0.f;
        for (int i = 0; i < B_DIM * E_DIM; ++i) { float d = sv[i] - mean; ss += d * d; }
        const float sd = sqrtf(ss * (1.f / (B_DIM * E_DIM - 1)));  // ddof=1
        const float z = ws[0] * (1.f / ((float)N_TOK * E_DIM));
        out_loss[0] = 0.001f * z + 0.1f * (sd / mean) * 10.f;
    }
}

extern "C" void kernel_launch(void* const* d_in, const int* in_sizes, int n_in,
                              void* d_out, int out_size, void* d_ws, size_t ws_size,
                              hipStream_t stream) {
    const float* x     = (const float*)d_in[0];
    const float* W     = (const float*)d_in[1];
    const float* gamma = (const float*)d_in[2];
    const float* beta  = (const float*)d_in[3];
    const float* temp  = (const float*)d_in[4];
    float* out  = (float*)d_out;
    float* rw   = out;                                  // routing_weights [N, E]
    float* dp   = out + (size_t)N_TOK * E_DIM;          // dispatch [B, S, E]
    float* loss = out + 2 * (size_t)N_TOK * E_DIM;      // total_loss scalar
    float* ws   = (float*)d_ws;   // [0]=zsum, [8..264)=load sums

    // workspace: [0,4KB) header | [4KB, +8MB) W-hi x32 copies | +8MB W-lo x32 copies
    unsigned short* whg = (unsigned short*)((char*)d_ws + 4096);
    unsigned short* wlg = whg + (size_t)NCOPY * WPLANE;

    wsplit<<<dim3(64), dim3(256), 0, stream>>>(W, whg, wlg, ws);  // also zeros header
    router_main<<<dim3(NBLK), dim3(NTHR), 0, stream>>>(x, W, whg, wlg, gamma, beta, temp,
                                                       rw, dp, ws, ws + 8);
    router_fin<<<dim3(1), dim3(256), 0, stream>>>(ws, loss);
}

// Round 13
// 227.346 us; speedup vs baseline: 1.0935x; 1.0728x over previous
//
#include <hip/hip_runtime.h>
#include <hip/hip_bf16.h>
#include <float.h>
#include <math.h>

// B=4, S=4096, D=2048, E=64, K=2
#define B_DIM 4
#define S_DIM 4096
#define D_DIM 2048
#define E_DIM 64
#define N_TOK 16384
#define TOKS 32              // tokens per block
#define NBLK (N_TOK / TOKS)  // 512 blocks (2/CU)
#define NTHR 512             // 8 waves: (token-half g) x (D-slice sl)
#define SLICES 4             // split-K factor
#define DSLICE (D_DIM / SLICES)  // 512
#define KSTEPS2 16           // K=32 per step, double-buffered LDS
#define GAP_THRESH 1e-3f
#define MAXFLAG 16

typedef __bf16 bf16x8_t __attribute__((ext_vector_type(8)));
typedef float f32x4_t __attribute__((ext_vector_type(4)));

union U8 { bf16x8_t v; unsigned short u[8]; };

// truncating fp32 -> (bf16 hi, bf16 lo) split; hi+lo captures ~16 mantissa bits
__device__ __forceinline__ void split2(float f, unsigned short& h, unsigned short& l) {
    unsigned int u = __float_as_uint(f);
    h = (unsigned short)(u >> 16);
    float hf = __uint_as_float(u & 0xFFFF0000u);
    l = (unsigned short)(__float_as_uint(f - hf) >> 16);  // exact residual (Sterbenz)
}

// async 16B global->LDS DMA (no VGPR round-trip, no spill pressure)
typedef const __attribute__((address_space(1))) unsigned int* gas1_t;
typedef __attribute__((address_space(3))) unsigned int* las3_t;
__device__ __forceinline__ void gll16(const unsigned short* g, unsigned short* l) {
    __builtin_amdgcn_global_load_lds((gas1_t)(const void*)g, (las3_t)(void*)l, 16, 0, 0);
}

// one-time W -> (hi,lo) bf16 planes in MFMA-fragment order (verified round 3/5/6):
//   elem offset = (((sl*8 + s)*2 + h)*4 + t)*512 + lane*8,  lane = quad*16 + l15
//   element source: expert e = t*16+l15, k = sl*512 + s*64 + h*32 + quad*8 + j
// Block 0 also zeros the ws header (zsum, block counter, load sums).
__global__ void wsplit(const float* __restrict__ W, unsigned short* __restrict__ wh,
                       unsigned short* __restrict__ wl, float* __restrict__ wshdr) {
    const int i = blockIdx.x * 256 + threadIdx.x;   // 0..16383
    if (blockIdx.x == 0) { wshdr[threadIdx.x] = 0.f; wshdr[threadIdx.x + 256] = 0.f; }
    const int e    = i >> 8;        // expert row 0..63
    const int k8   = i & 255;       // 8-float chunk 0..255
    const int quad = k8 & 3;
    const int h    = (k8 >> 2) & 1;
    const int s    = (k8 >> 3) & 7;
    const int sl   = k8 >> 6;
    const int t    = e >> 4;
    const int l15  = e & 15;
    const int lane = quad * 16 + l15;
    const size_t f = ((size_t)((sl * 8 + s) * 2 + h) * 4 + t) * 64 + lane;
    float4 a = *(const float4*)(W + (size_t)e * D_DIM + k8 * 8);
    float4 b = *(const float4*)(W + (size_t)e * D_DIM + k8 * 8 + 4);
    ushort4 h0, l0, h1, l1;
    split2(a.x, h0.x, l0.x); split2(a.y, h0.y, l0.y);
    split2(a.z, h0.z, l0.z); split2(a.w, h0.w, l0.w);
    split2(b.x, h1.x, l1.x); split2(b.y, h1.y, l1.y);
    split2(b.z, h1.z, l1.z); split2(b.w, h1.w, l1.w);
    *(ushort4*)(wh + f * 8)     = h0;
    *(ushort4*)(wh + f * 8 + 4) = h1;
    *(ushort4*)(wl + f * 8)     = l0;
    *(ushort4*)(wl + f * 8 + 4) = l1;
}

__global__ __launch_bounds__(NTHR, 4) void router_main(
    const float* __restrict__ x, const float* __restrict__ W,
    const unsigned short* __restrict__ whg, const unsigned short* __restrict__ wlg,
    const float* __restrict__ gamma, const float* __restrict__ beta,
    const float* __restrict__ temperature,
    float* __restrict__ out_rw, float* __restrict__ out_dp,
    float* __restrict__ g_zsum, float* __restrict__ g_load)
{
    // 64 KB arena: double-buffered W step-tiles (hi+lo, frag-order) during the K-loop;
    // split-K partials + logits afterwards (aliased — barrier separates lifetimes).
    __shared__ __align__(16) unsigned char arena[65536];
    unsigned short* const bufH = (unsigned short*)arena;            // [2][4][2048]
    unsigned short* const bufL = (unsigned short*)(arena + 32768);  // [2][4][2048]
    float (* const part)[TOKS][E_DIM + 2] = (float (*)[TOKS][E_DIM + 2])arena; // [4][32][66]
    float (* const lgt)[E_DIM + 1] = (float (*)[E_DIM + 1])(arena + 33792);    // [32][65]

    __shared__ float lgm[E_DIM], lbt[E_DIM], loadsum[E_DIM];
    __shared__ float smu[TOKS], srs[TOKS], sinv[TOKS];
    __shared__ int sel1[TOKS], sel2[TOKS];
    __shared__ int ftok[MAXFLAG], fcand[MAXFLAG][3];
    __shared__ int nflag;

    const int tid = threadIdx.x;
    const int tokBase = blockIdx.x * TOKS;
    const int lane = tid & 63;
    const int wv = tid >> 6;       // 0..7
    const int g  = wv & 1;         // token half: tokens g*16 .. g*16+15
    const int sl = wv >> 1;        // D-slice 0..3
    const int l15 = lane & 15;
    const int quad = lane >> 4;

    if (tid == 0) nflag = 0;
    if (tid < E_DIM) { lgm[tid] = gamma[tid]; lbt[tid] = beta[tid]; loadsum[tid] = 0.f; }

    // x per-lane A-fragment base: row = token, col = slice base + quad*8
    const float* xp = x + (size_t)(tokBase + g * 16 + l15) * D_DIM + sl * DSLICE + quad * 8;

    // DMA staging geometry: per step, per plane, tile = 4 slices x 2048 elems (4 KB each).
    // Thread tid covers slices kk0 and kk0+2 at elem offset soff (16 B per lane, linear):
    // LDS dst = wave-uniform base + lane*16B (matches global_load_lds HW pattern).
    const int kk0  = tid >> 8;            // 0..1
    const int soff = (tid & 255) * 8;

    f32x4_t acc[4];
    #pragma unroll
    for (int t = 0; t < 4; ++t) acc[t] = (f32x4_t){0.f, 0.f, 0.f, 0.f};

#define STAGE(S2, B) do {                                                          \
        const size_t gof = (size_t)(S2) * 2048 + soff;                             \
        unsigned short* hB = bufH + (B) * 8192;                                    \
        unsigned short* lB = bufL + (B) * 8192;                                    \
        gll16(whg + (size_t)kk0 * 32768 + gof,       hB + kk0 * 2048 + soff);      \
        gll16(wlg + (size_t)kk0 * 32768 + gof,       lB + kk0 * 2048 + soff);      \
        gll16(whg + (size_t)(kk0 + 2) * 32768 + gof, hB + (kk0 + 2) * 2048 + soff);\
        gll16(wlg + (size_t)(kk0 + 2) * 32768 + gof, lB + (kk0 + 2) * 2048 + soff);\
    } while (0)

    // ---- T3+T4 pipelined K-loop: raw barriers + COUNTED vmcnt (never 0) ----
    // Per-wave VMEM issue order (steady state, iter s): [x(s+1) x2] ... [D(s+2) x4].
    // At the post-STAGE wait, ops newer than D(s+1) = x(s+1)(2) + D(s+2)(4) = 6,
    // so vmcnt(6) forces exactly D(s+1) complete while 6 ops stay in flight.
    // prologue: stage tiles 0 and 1, load x(0); wait D(0) (newer: x(0)x2 + D(1)x4 = 6)
    STAGE(0, 0);
    float4 xqA0 = *(const float4*)(xp);
    float4 xqA1 = *(const float4*)(xp + 4);
    STAGE(1, 1);
    asm volatile("s_waitcnt vmcnt(6)" ::: "memory");
    __builtin_amdgcn_sched_barrier(0);
    __builtin_amdgcn_s_barrier();

    float4 xqB0, xqB1;
    #pragma unroll
    for (int s2 = 0; s2 < KSTEPS2; ++s2) {
        const int cur = s2 & 1;
        if (s2 + 1 < KSTEPS2) {   // issue next x load; consumed next iter
            const float* xg = xp + (s2 + 1) * 32;
            xqB0 = *(const float4*)(xg);
            xqB1 = *(const float4*)(xg + 4);
        }
        // compute tile s2 from buf[cur]: lane-contiguous ds_read_b128, conflict-free
        const unsigned short* hb = bufH + cur * 8192 + sl * 2048;
        const unsigned short* lb = bufL + cur * 8192 + sl * 2048;
        bf16x8_t bh[4], bl[4];
        #pragma unroll
        for (int t = 0; t < 4; ++t) {
            bh[t] = *(const bf16x8_t*)(hb + t * 512 + lane * 8);
            bl[t] = *(const bf16x8_t*)(lb + t * 512 + lane * 8);
        }
        float tf[8] = {xqA0.x, xqA0.y, xqA0.z, xqA0.w, xqA1.x, xqA1.y, xqA1.z, xqA1.w};
        U8 ah, al;
        #pragma unroll
        for (int k = 0; k < 8; ++k) split2(tf[k], ah.u[k], al.u[k]);
        #pragma unroll
        for (int t = 0; t < 4; ++t) {
            acc[t] = __builtin_amdgcn_mfma_f32_16x16x32_bf16(ah.v, bh[t], acc[t], 0, 0, 0);
            acc[t] = __builtin_amdgcn_mfma_f32_16x16x32_bf16(ah.v, bl[t], acc[t], 0, 0, 0);
            acc[t] = __builtin_amdgcn_mfma_f32_16x16x32_bf16(al.v, bh[t], acc[t], 0, 0, 0);
        }
        __builtin_amdgcn_s_barrier();          // all waves done reading buf[cur]
        if (s2 + 2 < KSTEPS2) {
            STAGE(s2 + 2, cur);                // refill the just-freed buffer
            asm volatile("s_waitcnt vmcnt(6)" ::: "memory");   // D(s2+1) done
        } else if (s2 + 1 < KSTEPS2) {
            asm volatile("s_waitcnt vmcnt(2)" ::: "memory");   // tail: only x(s2+1) newer
        }
        __builtin_amdgcn_sched_barrier(0);
        __builtin_amdgcn_s_barrier();          // D(s2+1) visible to all waves
        xqA0 = xqB0; xqA1 = xqB1;
    }
#undef STAGE

    __syncthreads();   // loop done (all DMA landed); protect wbuf -> part alias

    // phase A: partial acc -> LDS.  C/D: col(n)=lane&15, row(m)=quad*4+reg
    #pragma unroll
    for (int t = 0; t < 4; ++t)
        #pragma unroll
        for (int r = 0; r < 4; ++r)
            part[sl][g * 16 + quad * 4 + r][t * 16 + l15] = acc[t][r];
    __syncthreads();

    // split-K reduction: 4 partials -> logits (fixed pairwise order, deterministic)
    for (int i = tid; i < TOKS * E_DIM; i += NTHR) {
        int r = i >> 6, c = i & 63;
        lgt[r][c] = (part[0][r][c] + part[1][r][c]) + (part[2][r][c] + part[3][r][c]);
    }
    __syncthreads();

    // phase B: waves 0-1 only; 4 lanes per token (quad = expert quarter)
    if (wv < 2) {
        const int tok = wv * 16 + l15;
        const int q = quad;
        const float it = 1.f / (temperature[0] + 1e-6f);
        float s1 = 0.f, s2 = 0.f;
        #pragma unroll
        for (int e = 0; e < 16; ++e) { float v = lgt[tok][q * 16 + e]; s1 += v; s2 += v * v; }
        s1 += __shfl_xor(s1, 16); s1 += __shfl_xor(s1, 32);
        s2 += __shfl_xor(s2, 16); s2 += __shfl_xor(s2, 32);
        const float mu  = s1 * (1.f / 64.f);
        const float var = s2 * (1.f / 64.f) - mu * mu;   // biased, matches ref
        const float rs  = rsqrtf(var + 1e-5f);
        if (q == 0) { smu[tok] = mu; srs[tok] = rs; }

        float m0 = -FLT_MAX, m1 = -FLT_MAX, m2 = -FLT_MAX;
        int   i0 = -1, i1 = -1, i2 = -1;
        float zl = 0.f;
        #pragma unroll
        for (int e = 0; e < 16; ++e) {
            int c = q * 16 + e;
            float y = (lgt[tok][c] - mu) * rs * lgm[c] + lbt[c];
            lgt[tok][c] = y;
            zl += y * y;
            if (y > m0)      { m2 = m1; i2 = i1; m1 = m0; i1 = i0; m0 = y; i0 = c; }
            else if (y > m1) { m2 = m1; i2 = i1; m1 = y; i1 = c; }
            else if (y > m2) { m2 = y; i2 = c; }
        }
        // merge sorted top-3 triples across quad lanes (3+3 merge, low-index tie-break)
        #pragma unroll
        for (int d = 16; d <= 32; d <<= 1) {
            float n0 = __shfl_xor(m0, d), n1 = __shfl_xor(m1, d), n2 = __shfl_xor(m2, d);
            int   j0 = __shfl_xor(i0, d), j1 = __shfl_xor(i1, d), j2 = __shfl_xor(i2, d);
            bool t0 = (m0 > n0) || (m0 == n0 && i0 < j0);
            float r0v = t0 ? m0 : n0; int r0i = t0 ? i0 : j0;
            float A0v = t0 ? m1 : m0; int A0i = t0 ? i1 : i0;
            float A1v = t0 ? m2 : m1; int A1i = t0 ? i2 : i1;
            float B0v = t0 ? n0 : n1; int B0i = t0 ? j0 : j1;
            float B1v = t0 ? n1 : n2; int B1i = t0 ? j1 : j2;
            bool t1 = (A0v > B0v) || (A0v == B0v && A0i < B0i);
            float r1v = t1 ? A0v : B0v; int r1i = t1 ? A0i : B0i;
            float A0w = t1 ? A1v : A0v; int A0j = t1 ? A1i : A0i;
            float B0w = t1 ? B0v : B1v; int B0j = t1 ? B0i : B1i;
            bool t2 = (A0w > B0w) || (A0w == B0w && A0j < B0j);
            float r2v = t2 ? A0w : B0w; int r2i = t2 ? A0j : B0j;
            m0 = r0v; i0 = r0i; m1 = r1v; i1 = r1i; m2 = r2v; i2 = r2i;
        }
        if (q == 0) {
            sel1[tok] = i0; sel2[tok] = i1;
            if (m1 - m2 < GAP_THRESH) {   // rank2/rank3 near-tie -> fp64 fix-up
                int sf = atomicAdd(&nflag, 1);
                if (sf < MAXFLAG) { ftok[sf] = tok; fcand[sf][0] = i0; fcand[sf][1] = i1; fcand[sf][2] = i2; }
            }
        }
        // softmax (store unnormalized exp; scale at write time)
        float es = 0.f;
        #pragma unroll
        for (int e = 0; e < 16; ++e) {
            int c = q * 16 + e;
            float ev = __expf((lgt[tok][c] - m0) * it);
            lgt[tok][c] = ev; es += ev;
        }
        es += __shfl_xor(es, 16); es += __shfl_xor(es, 32);
        if (q == 0) sinv[tok] = 1.f / es;
        // z-loss: full-wave reduce (covers this wave's 16 tokens x 64 experts)
        zl += __shfl_xor(zl, 1); zl += __shfl_xor(zl, 2); zl += __shfl_xor(zl, 4);
        zl += __shfl_xor(zl, 8); zl += __shfl_xor(zl, 16); zl += __shfl_xor(zl, 32);
        if (lane == 0) atomicAdd(g_zsum, zl);
    }
    __syncthreads();

    // phase C: cooperative fp64 re-rank of flagged tokens' top-3 candidates (8 waves)
    const int nf = min(nflag, MAXFLAG);
    for (int f = wv; f < nf; f += 8) {
        const int tk = ftok[f];
        const int c0 = fcand[f][0], c1 = fcand[f][1], c2 = fcand[f][2];
        const float* xr = x + (size_t)(tokBase + tk) * D_DIM;
        const float* w0 = W + (size_t)c0 * D_DIM;
        const float* w1 = W + (size_t)c1 * D_DIM;
        const float* w2 = W + (size_t)c2 * D_DIM;
        double L0 = 0.0, L1 = 0.0, L2 = 0.0;
        for (int i = lane; i < D_DIM; i += 64) {
            double xv = (double)xr[i];
            L0 += xv * (double)w0[i];
            L1 += xv * (double)w1[i];
            L2 += xv * (double)w2[i];
        }
        #pragma unroll
        for (int off = 32; off; off >>= 1) {
            L0 += __shfl_down(L0, off);
            L1 += __shfl_down(L1, off);
            L2 += __shfl_down(L2, off);
        }
        if (lane == 0) {
            double dmu = (double)smu[tk], drs = (double)srs[tk];
            double y0 = (L0 - dmu) * drs * (double)lgm[c0] + (double)lbt[c0];
            double y1 = (L1 - dmu) * drs * (double)lgm[c1] + (double)lbt[c1];
            double y2 = (L2 - dmu) * drs * (double)lgm[c2] + (double)lbt[c2];
            bool g01 = (y0 > y1) || (y0 == y1 && c0 < c1);
            bool g02 = (y0 > y2) || (y0 == y2 && c0 < c2);
            bool g12 = (y1 > y2) || (y1 == y2 && c1 < c2);
            int a, b;
            if (!g01 && !g02)      { a = c1; b = c2; }   // elem0 loses both
            else if (g01 && !g12)  { a = c0; b = c2; }   // elem1 loses both
            else                   { a = c0; b = c1; }   // elem2 loses both
            sel1[tk] = a; sel2[tk] = b;
        }
    }
    __syncthreads();

    // phase D: expert-load accumulation (selection-dependent, post-fix-up)
    if (tid < TOKS) {
        float inv = sinv[tid];
        atomicAdd(&loadsum[sel1[tid]], lgt[tid][sel1[tid]] * inv);
        atomicAdd(&loadsum[sel2[tid]], lgt[tid][sel2[tid]] * inv);
    }
    __syncthreads();
    if (tid < E_DIM) atomicAdd(&g_load[(tokBase >> 12) * E_DIM + tid], loadsum[tid]);

    // phase E: coalesced outputs (8 KB per array per block)
    float* orw = out_rw + (size_t)tokBase * E_DIM;
    float* odp = out_dp + (size_t)tokBase * E_DIM;
    for (int i = tid; i < TOKS * E_DIM; i += NTHR) {
        int r = i >> 6, c = i & 63;
        float p = lgt[r][c] * sinv[r];
        orw[i] = p;
        odp[i] = (c == sel1[r] || c == sel2[r]) ? p : 0.f;
    }
}

__global__ void router_fin(const float* __restrict__ ws, float* __restrict__ out_loss) {
    __shared__ float sv[B_DIM * E_DIM];
    const int tid = threadIdx.x;
    sv[tid] = ws[8 + tid] * (1.f / S_DIM);   // expert_load[b][e]
    __syncthreads();
    if (tid == 0) {
        float s = 0.f;
        for (int i = 0; i < B_DIM * E_DIM; ++i) s += sv[i];
        const float mean = s * (1.f / (B_DIM * E_DIM));
        float ss = 0.f;
        for (int i = 0; i < B_DIM * E_DIM; ++i) { float d = sv[i] - mean; ss += d * d; }
        const float sd = sqrtf(ss * (1.f / (B_DIM * E_DIM - 1)));  // ddof=1
        const float z = ws[0] * (1.f / ((float)N_TOK * E_DIM));
        out_loss[0] = 0.001f * z + 0.1f * (sd / mean) * 10.f;
    }
}

extern "C" void kernel_launch(void* const* d_in, const int* in_sizes, int n_in,
                              void* d_out, int out_size, void* d_ws, size_t ws_size,
                              hipStream_t stream) {
    const float* x     = (const float*)d_in[0];
    const float* W     = (const float*)d_in[1];
    const float* gamma = (const float*)d_in[2];
    const float* beta  = (const float*)d_in[3];
    const float* temp  = (const float*)d_in[4];
    float* out  = (float*)d_out;
    float* rw   = out;                                  // routing_weights [N, E]
    float* dp   = out + (size_t)N_TOK * E_DIM;          // dispatch [B, S, E]
    float* loss = out + 2 * (size_t)N_TOK * E_DIM;      // total_loss scalar
    float* ws   = (float*)d_ws;   // [0]=zsum, [8..264)=load sums

    // workspace layout: [0,2KB) header | [4KB, +256KB) W-hi frag-order | +256KB W-lo
    unsigned short* whg = (unsigned short*)((char*)d_ws + 4096);
    unsigned short* wlg = whg + (size_t)E_DIM * D_DIM;

    wsplit<<<dim3(64), dim3(256), 0, stream>>>(W, whg, wlg, ws);  // also zeros header
    router_main<<<dim3(NBLK), dim3(NTHR), 0, stream>>>(x, W, whg, wlg, gamma, beta, temp,
                                                       rw, dp, ws, ws + 8);
    router_fin<<<dim3(1), dim3(256), 0, stream>>>(ws, loss);
}